// Round 1
// 93.258 us; speedup vs baseline: 1.0073x; 1.0073x over previous
//
#include <hip/hip_runtime.h>
#include <stdint.h>

#define N_AGENTS 4096
#define TOPK 12
#define EPSF 1e-4f
#define SURV_CAP 256

typedef unsigned long long u64;
typedef _Float16 half8 __attribute__((ext_vector_type(8)));
typedef float floatx4 __attribute__((ext_vector_type(4)));

static __device__ __forceinline__ u64 umin64(u64 a, u64 b) { return a < b ? a : b; }

// ---- 32-bit cross-lane xor exchange (J<=16 swizzle, J=32 bpermute) ----
template <int J>
static __device__ __forceinline__ uint32_t xswap32(uint32_t v, int bpaddr) {
    if constexpr (J == 32) {
        return (uint32_t)__builtin_amdgcn_ds_bpermute(bpaddr, (int)v);
    } else {
        constexpr int imm = 0x1F | (J << 10);
        return (uint32_t)__builtin_amdgcn_ds_swizzle((int)v, imm);
    }
}

// Paired compare-exchange stage: two independent bitonic networks advance in
// lockstep so the two swizzle latencies overlap (ILP), amortizing the serial
// 21-stage chain across both rows the block owns.
template <int K, int J>
static __device__ __forceinline__ void ce2(uint32_t& a, uint32_t& b, int lane, int bpaddr) {
    const uint32_t oa = xswap32<J>(a, bpaddr);
    const uint32_t ob = xswap32<J>(b, bpaddr);
    const bool up = (K == 64) ? true : ((lane & K) == 0);
    const bool keepmin = (((lane & J) == 0) == up);
    const uint32_t mna = a < oa ? a : oa;
    const uint32_t mxa = a < oa ? oa : a;
    const uint32_t mnb = b < ob ? b : ob;
    const uint32_t mxb = b < ob ? ob : b;
    a = keepmin ? mna : mxa;
    b = keepmin ? mnb : mxb;
}

static __device__ __forceinline__ void bitonic64_u32x2(uint32_t& a, uint32_t& b, int lane, int bpaddr) {
    ce2<2, 1>(a, b, lane, bpaddr);
    ce2<4, 2>(a, b, lane, bpaddr);
    ce2<4, 1>(a, b, lane, bpaddr);
    ce2<8, 4>(a, b, lane, bpaddr);
    ce2<8, 2>(a, b, lane, bpaddr);
    ce2<8, 1>(a, b, lane, bpaddr);
    ce2<16, 8>(a, b, lane, bpaddr);
    ce2<16, 4>(a, b, lane, bpaddr);
    ce2<16, 2>(a, b, lane, bpaddr);
    ce2<16, 1>(a, b, lane, bpaddr);
    ce2<32, 16>(a, b, lane, bpaddr);
    ce2<32, 8>(a, b, lane, bpaddr);
    ce2<32, 4>(a, b, lane, bpaddr);
    ce2<32, 2>(a, b, lane, bpaddr);
    ce2<32, 1>(a, b, lane, bpaddr);
    ce2<64, 32>(a, b, lane, bpaddr);
    ce2<64, 16>(a, b, lane, bpaddr);
    ce2<64, 8>(a, b, lane, bpaddr);
    ce2<64, 4>(a, b, lane, bpaddr);
    ce2<64, 2>(a, b, lane, bpaddr);
    ce2<64, 1>(a, b, lane, bpaddr);
}

// ---- 64-bit variants (exact final sort: key = (sqrt_bits<<32)|j) ----
template <int J>
static __device__ __forceinline__ u64 xswap64(u64 v, int bpaddr) {
    int lo = (int)(unsigned int)(v & 0xffffffffULL);
    int hi = (int)(unsigned int)(v >> 32);
    int nlo, nhi;
    if constexpr (J == 32) {
        nlo = __builtin_amdgcn_ds_bpermute(bpaddr, lo);
        nhi = __builtin_amdgcn_ds_bpermute(bpaddr, hi);
    } else {
        constexpr int imm = 0x1F | (J << 10);
        nlo = __builtin_amdgcn_ds_swizzle(lo, imm);
        nhi = __builtin_amdgcn_ds_swizzle(hi, imm);
    }
    return ((u64)(unsigned int)nhi << 32) | (unsigned int)nlo;
}

template <int K, int J>
static __device__ __forceinline__ u64 ce_stage(u64 v, int lane, int bpaddr) {
    const u64 o = xswap64<J>(v, bpaddr);
    const bool up = (K == 64) ? true : ((lane & K) == 0);
    const bool keepmin = (((lane & J) == 0) == up);
    const bool lt = v < o;
    const u64 mn = lt ? v : o;
    const u64 mx = lt ? o : v;
    return keepmin ? mn : mx;
}

static __device__ __forceinline__ u64 bitonic64(u64 v, int lane, int bpaddr) {
    v = ce_stage<2, 1>(v, lane, bpaddr);
    v = ce_stage<4, 2>(v, lane, bpaddr);
    v = ce_stage<4, 1>(v, lane, bpaddr);
    v = ce_stage<8, 4>(v, lane, bpaddr);
    v = ce_stage<8, 2>(v, lane, bpaddr);
    v = ce_stage<8, 1>(v, lane, bpaddr);
    v = ce_stage<16, 8>(v, lane, bpaddr);
    v = ce_stage<16, 4>(v, lane, bpaddr);
    v = ce_stage<16, 2>(v, lane, bpaddr);
    v = ce_stage<16, 1>(v, lane, bpaddr);
    v = ce_stage<32, 16>(v, lane, bpaddr);
    v = ce_stage<32, 8>(v, lane, bpaddr);
    v = ce_stage<32, 4>(v, lane, bpaddr);
    v = ce_stage<32, 2>(v, lane, bpaddr);
    v = ce_stage<32, 1>(v, lane, bpaddr);
    v = ce_stage<64, 32>(v, lane, bpaddr);
    v = ce_stage<64, 16>(v, lane, bpaddr);
    v = ce_stage<64, 8>(v, lane, bpaddr);
    v = ce_stage<64, 4>(v, lane, bpaddr);
    v = ce_stage<64, 2>(v, lane, bpaddr);
    v = ce_stage<64, 1>(v, lane, bpaddr);
    return v;
}

static __device__ __forceinline__ u64 wavemin64(u64 v, int bpaddr) {
    v = umin64(v, xswap64<1>(v, bpaddr));
    v = umin64(v, xswap64<2>(v, bpaddr));
    v = umin64(v, xswap64<4>(v, bpaddr));
    v = umin64(v, xswap64<8>(v, bpaddr));
    v = umin64(v, xswap64<16>(v, bpaddr));
    v = umin64(v, xswap64<32>(v, bpaddr));
    return v;
}

// Dense (x,y) pack: 32 KB footprint -> fully L1-resident for the topk scan,
// and scan loads become 8B-dense instead of 8-of-16B strided.
__global__ __launch_bounds__(256) void pack_kernel(const float* __restrict__ states,
                                                   float2* __restrict__ xy) {
    const int g = blockIdx.x * 256 + threadIdx.x;
    const float2* st2 = (const float2*)states;
    xy[g] = st2[g * 2];
}

// Two rows per block (2048 blocks) + 2 tail blocks that repack W2/W3 to
// transposed f16 concurrently (mlp consumes them; same-stream ordering).
// Stage 1 runs entirely in the d^2 domain (positive floats: uint order ==
// float order; sqrt is monotone, so the 12th-of-64-lane-minima bound holds
// identically). sqrt is computed only for the ~13 survivors per row; the
// final exact sort key (sqrt_bits<<32)|j is bit-identical to before. The
// +8-ulp slack on the d^2 threshold covers the sqrt tie-class preimage
// (<= ~4 ulps), keeping the survivor set a superset of the true top-12.
__global__ __launch_bounds__(256) void topk_kernel(
    const float2* __restrict__ xy,
    const float* __restrict__ W2, const float* __restrict__ W3,
    _Float16* __restrict__ W2T, _Float16* __restrict__ W3T,
    int* __restrict__ idx_out, float* __restrict__ dist_out) {
    const int b = blockIdx.x;
    const int t = threadIdx.x;

    if (b >= N_AGENTS / 2) {  // weight repack tail blocks (run concurrently)
        if (b == N_AGENTS / 2) {
#pragma unroll
            for (int e = 0; e < 32; ++e) {
                const int o = t + e * 256;  // o = n*64 + k
                W2T[o] = (_Float16)W2[(o & 63) * 128 + (o >> 6)];
            }
        } else {
#pragma unroll
            for (int e = 0; e < 32; ++e) {
                const int o = t + e * 256;  // o = n*128 + k
                W3T[o] = (_Float16)W3[(o & 127) * 64 + (o >> 7)];
            }
        }
        return;
    }

    const int lane = t & 63;
    const int wv = t >> 6;
    const int bpaddr = (lane ^ 32) << 2;
    const int i0 = b * 2;
    const float2 me0 = xy[i0];
    const float2 me1 = xy[i0 + 1];

    uint32_t dA[16], dB[16];
#pragma unroll
    for (int s = 0; s < 16; ++s) {
        const float2 p = xy[t + s * 256];
        {
            const float dx = me0.x - p.x;
            const float dy = me0.y - p.y;
            dA[s] = __float_as_uint((dx * dx + EPSF) + (dy * dy + EPSF));
        }
        {
            const float dx = me1.x - p.x;
            const float dy = me1.y - p.y;
            dB[s] = __float_as_uint((dx * dx + EPSF) + (dy * dy + EPSF));
        }
    }
    uint32_t l0 = dA[0], l1 = dB[0];
#pragma unroll
    for (int s = 1; s < 16; ++s) {
        l0 = dA[s] < l0 ? dA[s] : l0;
        l1 = dB[s] < l1 ? dB[s] : l1;
    }

    __shared__ uint32_t wb[2][4];
    __shared__ u64 surv[2][SURV_CAP];
    __shared__ int cnt[2];

    // 12th smallest of this wave's 64 lane-minima = provable upper bound on
    // the row's 12th smallest d^2 (12 distinct candidates <= it).
    bitonic64_u32x2(l0, l1, lane, bpaddr);
    if (lane == 11) {
        wb[0][wv] = l0;
        wb[1][wv] = l1;
    }
    if (t < 2) cnt[t] = 0;
    __syncthreads();

    uint32_t U0 = wb[0][0];
    U0 = wb[0][1] < U0 ? wb[0][1] : U0;
    U0 = wb[0][2] < U0 ? wb[0][2] : U0;
    U0 = wb[0][3] < U0 ? wb[0][3] : U0;
    uint32_t U1 = wb[1][0];
    U1 = wb[1][1] < U1 ? wb[1][1] : U1;
    U1 = wb[1][2] < U1 ? wb[1][2] : U1;
    U1 = wb[1][3] < U1 ? wb[1][3] : U1;
    U0 += 8;  // sqrt tie-class slack (preimage of one sqrt output <= ~4 ulps)
    U1 += 8;

#pragma unroll
    for (int s = 0; s < 16; ++s) {
        const unsigned int j = (unsigned int)(t + s * 256);
        if (dA[s] <= U0) {
            const int p = atomicAdd(&cnt[0], 1);
            if (p < SURV_CAP) {
                const uint32_t sb = __float_as_uint(sqrtf(__uint_as_float(dA[s])));
                surv[0][p] = ((u64)sb << 32) | j;
            }
        }
        if (dB[s] <= U1) {
            const int p = atomicAdd(&cnt[1], 1);
            if (p < SURV_CAP) {
                const uint32_t sb = __float_as_uint(sqrtf(__uint_as_float(dB[s])));
                surv[1][p] = ((u64)sb << 32) | j;
            }
        }
    }
    __syncthreads();

    if (wv < 2) {  // waves 0/1 finish rows 0/1 concurrently
        const int r = wv;
        const int i = i0 + r;
        const int S = cnt[r];
        if (S <= 64) {
            u64 x = (lane < S) ? surv[r][lane] : ~0ULL;
            x = bitonic64(x, lane, bpaddr);
            if (lane < TOPK) {
                idx_out[i * TOPK + lane] = (int)(unsigned int)(x & 0xffffffffULL);
                dist_out[i * TOPK + lane] = __uint_as_float((unsigned int)(x >> 32));
            }
        } else {
            // cold fallback (S in (64, 256]): iterative extraction
            u64 a[4];
#pragma unroll
            for (int q = 0; q < 4; ++q)
                a[q] = (lane + 64 * q < S) ? surv[r][lane + 64 * q] : ~0ULL;
            u64 al = umin64(umin64(a[0], a[1]), umin64(a[2], a[3]));
            for (int k = 0; k < TOPK; ++k) {
                const u64 v = wavemin64(al, bpaddr);
                if (lane == 0) {
                    idx_out[i * TOPK + k] = (int)(unsigned int)(v & 0xffffffffULL);
                    dist_out[i * TOPK + k] = __uint_as_float((unsigned int)(v >> 32));
                }
                if (al == v) {
#pragma unroll
                    for (int q = 0; q < 4; ++q)
                        if (a[q] == v) a[q] = ~0ULL;
                    al = umin64(umin64(a[0], a[1]), umin64(a[2], a[3]));
                }
            }
        }
    }
}

// MLP: 64 edges per 256-thread block. L1 (6->64) in fp32 VALU; L2 (64->128)
// and L3 (128->64) as f16 MFMA 16x16x32 with fp32 accum; L4 (64->1) as
// per-lane dot + 16-lane swizzle reduction. B-fragments are now single 16B
// half8 loads from the pre-transposed f16 W2T/W3T (bit-identical to the old
// inline f32->f16 cast: same RTN cast, same (k,n) element).
__global__ __launch_bounds__(256) void mlp_kernel(
    const float* __restrict__ states,
    const int* __restrict__ idx_in,
    const float* __restrict__ dist_in,
    const float* __restrict__ W1, const float* __restrict__ b1,
    const _Float16* __restrict__ W2T, const float* __restrict__ b2,
    const _Float16* __restrict__ W3T, const float* __restrict__ b3,
    const float* __restrict__ W4, const float* __restrict__ b4,
    float* __restrict__ out) {
    __shared__ __align__(16) _Float16 h1s[64 * 72];    // [m=edge][k], pad 8
    __shared__ __align__(16) _Float16 h2s[64 * 136];   // [m=edge][k], pad 8
    __shared__ float partial[4 * 64];

    const int t = threadIdx.x;
    const int lane = t & 63;
    const int wv = __builtin_amdgcn_readfirstlane(t >> 6);
    const int quad = lane >> 4;
    const int l15 = lane & 15;
    const int e0 = blockIdx.x * 64;

    // B-fragment loads: 16x16x32 B layout, lane n = lane&15, 8 consecutive k
    // at ks*32 + quad*8 -> one contiguous half8 from the transposed weights.
    half8 b2f[2][2], b3f[4];
#pragma unroll
    for (int ks = 0; ks < 2; ++ks)
#pragma unroll
        for (int nt = 0; nt < 2; ++nt) {
            const int n = wv * 32 + nt * 16 + l15;
            b2f[ks][nt] = *(const half8*)&W2T[n * 64 + ks * 32 + quad * 8];
        }
    const int n3 = wv * 16 + l15;
#pragma unroll
    for (int ks = 0; ks < 4; ++ks)
        b3f[ks] = *(const half8*)&W3T[n3 * 128 + ks * 32 + quad * 8];

    // ---- layer 1 (fp32): edge = lane, this wave computes o in [16wv,16wv+16)
    const float d_edge = dist_in[e0 + lane];  // wave 0's copy reused in epilogue
    {
        const int e = e0 + lane;
        const int i = e / TOPK;
        const int j = idx_in[e];
        const float4 si = ((const float4*)states)[i];
        const float4 sj = ((const float4*)states)[j];
        float feat[6];
        feat[0] = si.x - sj.x;
        feat[1] = si.y - sj.y;
        feat[2] = si.z - sj.z;
        feat[3] = si.w - sj.w;
        feat[4] = (i == j) ? 1.0f : 0.0f;
        feat[5] = d_edge - 0.1f;

        _Float16 h1v[16];
#pragma unroll
        for (int oo = 0; oo < 16; ++oo) {
            const int o = wv * 16 + oo;
            float acc = b1[o];
#pragma unroll
            for (int f = 0; f < 6; ++f) acc += feat[f] * W1[f * 64 + o];
            h1v[oo] = (_Float16)fmaxf(acc, 0.0f);
        }
        half8* dst = (half8*)&h1s[lane * 72 + wv * 16];
        dst[0] = *(half8*)&h1v[0];
        dst[1] = *(half8*)&h1v[8];
    }
    __syncthreads();

    // ---- layer 2 (MFMA): C[m=64][n=wv*32 .. +32]
    floatx4 acc2[4][2];
#pragma unroll
    for (int mt = 0; mt < 4; ++mt)
#pragma unroll
        for (int nt = 0; nt < 2; ++nt) acc2[mt][nt] = (floatx4){0.f, 0.f, 0.f, 0.f};
#pragma unroll
    for (int ks = 0; ks < 2; ++ks)
#pragma unroll
        for (int mt = 0; mt < 4; ++mt) {
            const half8 a = *(const half8*)&h1s[(mt * 16 + l15) * 72 + ks * 32 + quad * 8];
            acc2[mt][0] = __builtin_amdgcn_mfma_f32_16x16x32_f16(a, b2f[ks][0], acc2[mt][0], 0, 0, 0);
            acc2[mt][1] = __builtin_amdgcn_mfma_f32_16x16x32_f16(a, b2f[ks][1], acc2[mt][1], 0, 0, 0);
        }
    float bias2[2] = {b2[wv * 32 + l15], b2[wv * 32 + 16 + l15]};
#pragma unroll
    for (int mt = 0; mt < 4; ++mt)
#pragma unroll
        for (int nt = 0; nt < 2; ++nt)
#pragma unroll
            for (int r = 0; r < 4; ++r) {
                const int m = mt * 16 + quad * 4 + r;
                const int n = wv * 32 + nt * 16 + l15;
                h2s[m * 136 + n] = (_Float16)fmaxf(acc2[mt][nt][r] + bias2[nt], 0.0f);
            }
    __syncthreads();

    // ---- layer 3 (MFMA): C[m=64][n=wv*16 .. +16]
    floatx4 acc3[4];
#pragma unroll
    for (int mt = 0; mt < 4; ++mt) acc3[mt] = (floatx4){0.f, 0.f, 0.f, 0.f};
#pragma unroll
    for (int ks = 0; ks < 4; ++ks)
#pragma unroll
        for (int mt = 0; mt < 4; ++mt) {
            const half8 a = *(const half8*)&h2s[(mt * 16 + l15) * 136 + ks * 32 + quad * 8];
            acc3[mt] = __builtin_amdgcn_mfma_f32_16x16x32_f16(a, b3f[ks], acc3[mt], 0, 0, 0);
        }

    // ---- layer 4: per-lane relu+dot, reduce over the 16 n's in each quad
    const float bias3 = b3[n3];
    const float w4v = W4[n3];
#pragma unroll
    for (int mt = 0; mt < 4; ++mt)
#pragma unroll
        for (int r = 0; r < 4; ++r) {
            float v = fmaxf(acc3[mt][r] + bias3, 0.0f) * w4v;
            v += __int_as_float(__builtin_amdgcn_ds_swizzle(__float_as_int(v), 0x041F));
            v += __int_as_float(__builtin_amdgcn_ds_swizzle(__float_as_int(v), 0x081F));
            v += __int_as_float(__builtin_amdgcn_ds_swizzle(__float_as_int(v), 0x101F));
            v += __int_as_float(__builtin_amdgcn_ds_swizzle(__float_as_int(v), 0x201F));
            if (l15 == 0) partial[wv * 64 + mt * 16 + quad * 4 + r] = v;
        }
    __syncthreads();

    if (t < 64) {  // wave 0: d_edge is dist_in[e0+t] already in register
        const float s = partial[t] + partial[64 + t] + partial[128 + t] + partial[192 + t] + b4[0];
        out[e0 + t] = (d_edge <= 1.0f) ? s : 0.0f;
    }
}

extern "C" void kernel_launch(void* const* d_in, const int* in_sizes, int n_in,
                              void* d_out, int out_size, void* d_ws, size_t ws_size,
                              hipStream_t stream) {
    const float* states = (const float*)d_in[0];
    const float* W1 = (const float*)d_in[1];
    const float* b1 = (const float*)d_in[2];
    const float* W2 = (const float*)d_in[3];
    const float* b2 = (const float*)d_in[4];
    const float* W3 = (const float*)d_in[5];
    const float* b3 = (const float*)d_in[6];
    const float* W4 = (const float*)d_in[7];
    const float* b4 = (const float*)d_in[8];

    char* ws = (char*)d_ws;
    int* idx = (int*)ws;                           // 192 KB
    float* dist = (float*)(ws + 192 * 1024);       // 192 KB
    _Float16* W2T = (_Float16*)(ws + 384 * 1024);  // 16 KB  [n=128][k=64]
    _Float16* W3T = (_Float16*)(ws + 400 * 1024);  // 16 KB  [n=64][k=128]
    float2* xy = (float2*)(ws + 416 * 1024);       // 32 KB

    pack_kernel<<<16, 256, 0, stream>>>(states, xy);
    topk_kernel<<<N_AGENTS / 2 + 2, 256, 0, stream>>>(xy, W2, W3, W2T, W3T, idx, dist);
    mlp_kernel<<<(N_AGENTS * TOPK) / 64, 256, 0, stream>>>(
        states, idx, dist, W1, b1, W2T, b2, W3T, b3, W4, b4, (float*)d_out);
}

// Round 2
// 90.224 us; speedup vs baseline: 1.0412x; 1.0336x over previous
//
#include <hip/hip_runtime.h>
#include <stdint.h>

#define N_AGENTS 4096
#define TOPK 12
#define EPSF 1e-4f
#define SURV_CAP 256

typedef unsigned long long u64;
typedef _Float16 half8 __attribute__((ext_vector_type(8)));
typedef float floatx4 __attribute__((ext_vector_type(4)));

static __device__ __forceinline__ u64 umin64(u64 a, u64 b) { return a < b ? a : b; }

// ---- 32-bit cross-lane xor exchange (J<=16 swizzle, J=32 bpermute) ----
template <int J>
static __device__ __forceinline__ uint32_t xswap32(uint32_t v, int bpaddr) {
    if constexpr (J == 32) {
        return (uint32_t)__builtin_amdgcn_ds_bpermute(bpaddr, (int)v);
    } else {
        constexpr int imm = 0x1F | (J << 10);
        return (uint32_t)__builtin_amdgcn_ds_swizzle((int)v, imm);
    }
}

// Paired compare-exchange stage: two independent bitonic networks advance in
// lockstep so the two swizzle latencies overlap (ILP), amortizing the serial
// 21-stage chain across both rows the block owns.
template <int K, int J>
static __device__ __forceinline__ void ce2(uint32_t& a, uint32_t& b, int lane, int bpaddr) {
    const uint32_t oa = xswap32<J>(a, bpaddr);
    const uint32_t ob = xswap32<J>(b, bpaddr);
    const bool up = (K == 64) ? true : ((lane & K) == 0);
    const bool keepmin = (((lane & J) == 0) == up);
    const uint32_t mna = a < oa ? a : oa;
    const uint32_t mxa = a < oa ? oa : a;
    const uint32_t mnb = b < ob ? b : ob;
    const uint32_t mxb = b < ob ? ob : b;
    a = keepmin ? mna : mxa;
    b = keepmin ? mnb : mxb;
}

static __device__ __forceinline__ void bitonic64_u32x2(uint32_t& a, uint32_t& b, int lane, int bpaddr) {
    ce2<2, 1>(a, b, lane, bpaddr);
    ce2<4, 2>(a, b, lane, bpaddr);
    ce2<4, 1>(a, b, lane, bpaddr);
    ce2<8, 4>(a, b, lane, bpaddr);
    ce2<8, 2>(a, b, lane, bpaddr);
    ce2<8, 1>(a, b, lane, bpaddr);
    ce2<16, 8>(a, b, lane, bpaddr);
    ce2<16, 4>(a, b, lane, bpaddr);
    ce2<16, 2>(a, b, lane, bpaddr);
    ce2<16, 1>(a, b, lane, bpaddr);
    ce2<32, 16>(a, b, lane, bpaddr);
    ce2<32, 8>(a, b, lane, bpaddr);
    ce2<32, 4>(a, b, lane, bpaddr);
    ce2<32, 2>(a, b, lane, bpaddr);
    ce2<32, 1>(a, b, lane, bpaddr);
    ce2<64, 32>(a, b, lane, bpaddr);
    ce2<64, 16>(a, b, lane, bpaddr);
    ce2<64, 8>(a, b, lane, bpaddr);
    ce2<64, 4>(a, b, lane, bpaddr);
    ce2<64, 2>(a, b, lane, bpaddr);
    ce2<64, 1>(a, b, lane, bpaddr);
}

// ---- 64-bit variants (exact final sort: key = (sqrt_bits<<32)|j) ----
template <int J>
static __device__ __forceinline__ u64 xswap64(u64 v, int bpaddr) {
    int lo = (int)(unsigned int)(v & 0xffffffffULL);
    int hi = (int)(unsigned int)(v >> 32);
    int nlo, nhi;
    if constexpr (J == 32) {
        nlo = __builtin_amdgcn_ds_bpermute(bpaddr, lo);
        nhi = __builtin_amdgcn_ds_bpermute(bpaddr, hi);
    } else {
        constexpr int imm = 0x1F | (J << 10);
        nlo = __builtin_amdgcn_ds_swizzle(lo, imm);
        nhi = __builtin_amdgcn_ds_swizzle(hi, imm);
    }
    return ((u64)(unsigned int)nhi << 32) | (unsigned int)nlo;
}

template <int K, int J>
static __device__ __forceinline__ u64 ce_stage(u64 v, int lane, int bpaddr) {
    const u64 o = xswap64<J>(v, bpaddr);
    const bool up = (K == 64) ? true : ((lane & K) == 0);
    const bool keepmin = (((lane & J) == 0) == up);
    const bool lt = v < o;
    const u64 mn = lt ? v : o;
    const u64 mx = lt ? o : v;
    return keepmin ? mn : mx;
}

static __device__ __forceinline__ u64 bitonic64(u64 v, int lane, int bpaddr) {
    v = ce_stage<2, 1>(v, lane, bpaddr);
    v = ce_stage<4, 2>(v, lane, bpaddr);
    v = ce_stage<4, 1>(v, lane, bpaddr);
    v = ce_stage<8, 4>(v, lane, bpaddr);
    v = ce_stage<8, 2>(v, lane, bpaddr);
    v = ce_stage<8, 1>(v, lane, bpaddr);
    v = ce_stage<16, 8>(v, lane, bpaddr);
    v = ce_stage<16, 4>(v, lane, bpaddr);
    v = ce_stage<16, 2>(v, lane, bpaddr);
    v = ce_stage<16, 1>(v, lane, bpaddr);
    v = ce_stage<32, 16>(v, lane, bpaddr);
    v = ce_stage<32, 8>(v, lane, bpaddr);
    v = ce_stage<32, 4>(v, lane, bpaddr);
    v = ce_stage<32, 2>(v, lane, bpaddr);
    v = ce_stage<32, 1>(v, lane, bpaddr);
    v = ce_stage<64, 32>(v, lane, bpaddr);
    v = ce_stage<64, 16>(v, lane, bpaddr);
    v = ce_stage<64, 8>(v, lane, bpaddr);
    v = ce_stage<64, 4>(v, lane, bpaddr);
    v = ce_stage<64, 2>(v, lane, bpaddr);
    v = ce_stage<64, 1>(v, lane, bpaddr);
    return v;
}

static __device__ __forceinline__ u64 wavemin64(u64 v, int bpaddr) {
    v = umin64(v, xswap64<1>(v, bpaddr));
    v = umin64(v, xswap64<2>(v, bpaddr));
    v = umin64(v, xswap64<4>(v, bpaddr));
    v = umin64(v, xswap64<8>(v, bpaddr));
    v = umin64(v, xswap64<16>(v, bpaddr));
    v = umin64(v, xswap64<32>(v, bpaddr));
    return v;
}

// Two rows per block (2048 blocks) + 2 tail blocks that repack W2/W3 to
// transposed f16 concurrently (mlp consumes them; cross-kernel ordering).
// Stage 1 runs entirely in the d^2 domain (positive floats: uint order ==
// float order; sqrt is monotone, so the 12th-of-64-lane-minima bound holds
// identically). sqrt is computed only for the ~13 survivors per row; the
// final exact sort key (sqrt_bits<<32)|j is bit-identical to the reference
// pipeline. The +8-ulp slack on the d^2 threshold covers the sqrt tie-class
// preimage (<= ~4 ulps), keeping survivors a superset of the true top-12.
// Scan reads states strided directly (8B of each 16B row): the scan is
// VALU-bound, not load-bound, so the earlier pack kernel was pure overhead.
__global__ __launch_bounds__(256) void topk_kernel(
    const float* __restrict__ states,
    const float* __restrict__ W2, const float* __restrict__ W3,
    _Float16* __restrict__ W2T, _Float16* __restrict__ W3T,
    int* __restrict__ idx_out, float* __restrict__ dist_out) {
    const int b = blockIdx.x;
    const int t = threadIdx.x;

    if (b >= N_AGENTS / 2) {  // weight repack tail blocks (run concurrently)
        if (b == N_AGENTS / 2) {
#pragma unroll
            for (int e = 0; e < 32; ++e) {
                const int o = t + e * 256;  // o = n*64 + k
                W2T[o] = (_Float16)W2[(o & 63) * 128 + (o >> 6)];
            }
        } else {
#pragma unroll
            for (int e = 0; e < 32; ++e) {
                const int o = t + e * 256;  // o = n*128 + k
                W3T[o] = (_Float16)W3[(o & 127) * 64 + (o >> 7)];
            }
        }
        return;
    }

    const int lane = t & 63;
    const int wv = t >> 6;
    const int bpaddr = (lane ^ 32) << 2;
    const int i0 = b * 2;
    const float2* st2 = (const float2*)states;  // [j*2] = (x,y)
    const float2 me0 = st2[i0 * 2];
    const float2 me1 = st2[(i0 + 1) * 2];

    uint32_t dA[16], dB[16];
#pragma unroll
    for (int s = 0; s < 16; ++s) {
        const float2 p = st2[(t + s * 256) * 2];
        {
            const float dx = me0.x - p.x;
            const float dy = me0.y - p.y;
            dA[s] = __float_as_uint((dx * dx + EPSF) + (dy * dy + EPSF));
        }
        {
            const float dx = me1.x - p.x;
            const float dy = me1.y - p.y;
            dB[s] = __float_as_uint((dx * dx + EPSF) + (dy * dy + EPSF));
        }
    }
    uint32_t l0 = dA[0], l1 = dB[0];
#pragma unroll
    for (int s = 1; s < 16; ++s) {
        l0 = dA[s] < l0 ? dA[s] : l0;
        l1 = dB[s] < l1 ? dB[s] : l1;
    }

    __shared__ uint32_t wb[2][4];
    __shared__ u64 surv[2][SURV_CAP];
    __shared__ int cnt[2];

    // 12th smallest of this wave's 64 lane-minima = provable upper bound on
    // the row's 12th smallest d^2 (12 distinct candidates <= it).
    bitonic64_u32x2(l0, l1, lane, bpaddr);
    if (lane == 11) {
        wb[0][wv] = l0;
        wb[1][wv] = l1;
    }
    if (t < 2) cnt[t] = 0;
    __syncthreads();

    uint32_t U0 = wb[0][0];
    U0 = wb[0][1] < U0 ? wb[0][1] : U0;
    U0 = wb[0][2] < U0 ? wb[0][2] : U0;
    U0 = wb[0][3] < U0 ? wb[0][3] : U0;
    uint32_t U1 = wb[1][0];
    U1 = wb[1][1] < U1 ? wb[1][1] : U1;
    U1 = wb[1][2] < U1 ? wb[1][2] : U1;
    U1 = wb[1][3] < U1 ? wb[1][3] : U1;
    U0 += 8;  // sqrt tie-class slack (preimage of one sqrt output <= ~4 ulps)
    U1 += 8;

#pragma unroll
    for (int s = 0; s < 16; ++s) {
        const unsigned int j = (unsigned int)(t + s * 256);
        if (dA[s] <= U0) {
            const int p = atomicAdd(&cnt[0], 1);
            if (p < SURV_CAP) {
                const uint32_t sb = __float_as_uint(sqrtf(__uint_as_float(dA[s])));
                surv[0][p] = ((u64)sb << 32) | j;
            }
        }
        if (dB[s] <= U1) {
            const int p = atomicAdd(&cnt[1], 1);
            if (p < SURV_CAP) {
                const uint32_t sb = __float_as_uint(sqrtf(__uint_as_float(dB[s])));
                surv[1][p] = ((u64)sb << 32) | j;
            }
        }
    }
    __syncthreads();

    if (wv < 2) {  // waves 0/1 finish rows 0/1 concurrently
        const int r = wv;
        const int i = i0 + r;
        const int S = cnt[r];
        if (S <= 64) {
            u64 x = (lane < S) ? surv[r][lane] : ~0ULL;
            x = bitonic64(x, lane, bpaddr);
            if (lane < TOPK) {
                idx_out[i * TOPK + lane] = (int)(unsigned int)(x & 0xffffffffULL);
                dist_out[i * TOPK + lane] = __uint_as_float((unsigned int)(x >> 32));
            }
        } else {
            // cold fallback (S in (64, 256]): iterative extraction
            u64 a[4];
#pragma unroll
            for (int q = 0; q < 4; ++q)
                a[q] = (lane + 64 * q < S) ? surv[r][lane + 64 * q] : ~0ULL;
            u64 al = umin64(umin64(a[0], a[1]), umin64(a[2], a[3]));
            for (int k = 0; k < TOPK; ++k) {
                const u64 v = wavemin64(al, bpaddr);
                if (lane == 0) {
                    idx_out[i * TOPK + k] = (int)(unsigned int)(v & 0xffffffffULL);
                    dist_out[i * TOPK + k] = __uint_as_float((unsigned int)(v >> 32));
                }
                if (al == v) {
#pragma unroll
                    for (int q = 0; q < 4; ++q)
                        if (a[q] == v) a[q] = ~0ULL;
                    al = umin64(umin64(a[0], a[1]), umin64(a[2], a[3]));
                }
            }
        }
    }
}

// MLP: 64 edges per 256-thread block. L1 (6->64) in fp32 VALU; L2 (64->128)
// and L3 (128->64) as f16 MFMA 16x16x32 with fp32 accum; L4 (64->1) as
// per-lane dot + 16-lane swizzle reduction. B-fragments are single 16B half8
// loads from the pre-transposed f16 W2T/W3T (bit-identical to an inline
// f32->f16 cast: same RTN cast, same (k,n) element).
__global__ __launch_bounds__(256) void mlp_kernel(
    const float* __restrict__ states,
    const int* __restrict__ idx_in,
    const float* __restrict__ dist_in,
    const float* __restrict__ W1, const float* __restrict__ b1,
    const _Float16* __restrict__ W2T, const float* __restrict__ b2,
    const _Float16* __restrict__ W3T, const float* __restrict__ b3,
    const float* __restrict__ W4, const float* __restrict__ b4,
    float* __restrict__ out) {
    __shared__ __align__(16) _Float16 h1s[64 * 72];    // [m=edge][k], pad 8
    __shared__ __align__(16) _Float16 h2s[64 * 136];   // [m=edge][k], pad 8
    __shared__ float partial[4 * 64];

    const int t = threadIdx.x;
    const int lane = t & 63;
    const int wv = __builtin_amdgcn_readfirstlane(t >> 6);
    const int quad = lane >> 4;
    const int l15 = lane & 15;
    const int e0 = blockIdx.x * 64;

    // B-fragment loads: 16x16x32 B layout, lane n = lane&15, 8 consecutive k
    // at ks*32 + quad*8 -> one contiguous half8 from the transposed weights.
    half8 b2f[2][2], b3f[4];
#pragma unroll
    for (int ks = 0; ks < 2; ++ks)
#pragma unroll
        for (int nt = 0; nt < 2; ++nt) {
            const int n = wv * 32 + nt * 16 + l15;
            b2f[ks][nt] = *(const half8*)&W2T[n * 64 + ks * 32 + quad * 8];
        }
    const int n3 = wv * 16 + l15;
#pragma unroll
    for (int ks = 0; ks < 4; ++ks)
        b3f[ks] = *(const half8*)&W3T[n3 * 128 + ks * 32 + quad * 8];

    // ---- layer 1 (fp32): edge = lane, this wave computes o in [16wv,16wv+16)
    const float d_edge = dist_in[e0 + lane];  // wave 0's copy reused in epilogue
    {
        const int e = e0 + lane;
        const int i = e / TOPK;
        const int j = idx_in[e];
        const float4 si = ((const float4*)states)[i];
        const float4 sj = ((const float4*)states)[j];
        float feat[6];
        feat[0] = si.x - sj.x;
        feat[1] = si.y - sj.y;
        feat[2] = si.z - sj.z;
        feat[3] = si.w - sj.w;
        feat[4] = (i == j) ? 1.0f : 0.0f;
        feat[5] = d_edge - 0.1f;

        _Float16 h1v[16];
#pragma unroll
        for (int oo = 0; oo < 16; ++oo) {
            const int o = wv * 16 + oo;
            float acc = b1[o];
#pragma unroll
            for (int f = 0; f < 6; ++f) acc += feat[f] * W1[f * 64 + o];
            h1v[oo] = (_Float16)fmaxf(acc, 0.0f);
        }
        half8* dst = (half8*)&h1s[lane * 72 + wv * 16];
        dst[0] = *(half8*)&h1v[0];
        dst[1] = *(half8*)&h1v[8];
    }
    __syncthreads();

    // ---- layer 2 (MFMA): C[m=64][n=wv*32 .. +32]
    floatx4 acc2[4][2];
#pragma unroll
    for (int mt = 0; mt < 4; ++mt)
#pragma unroll
        for (int nt = 0; nt < 2; ++nt) acc2[mt][nt] = (floatx4){0.f, 0.f, 0.f, 0.f};
#pragma unroll
    for (int ks = 0; ks < 2; ++ks)
#pragma unroll
        for (int mt = 0; mt < 4; ++mt) {
            const half8 a = *(const half8*)&h1s[(mt * 16 + l15) * 72 + ks * 32 + quad * 8];
            acc2[mt][0] = __builtin_amdgcn_mfma_f32_16x16x32_f16(a, b2f[ks][0], acc2[mt][0], 0, 0, 0);
            acc2[mt][1] = __builtin_amdgcn_mfma_f32_16x16x32_f16(a, b2f[ks][1], acc2[mt][1], 0, 0, 0);
        }
    float bias2[2] = {b2[wv * 32 + l15], b2[wv * 32 + 16 + l15]};
#pragma unroll
    for (int mt = 0; mt < 4; ++mt)
#pragma unroll
        for (int nt = 0; nt < 2; ++nt)
#pragma unroll
            for (int r = 0; r < 4; ++r) {
                const int m = mt * 16 + quad * 4 + r;
                const int n = wv * 32 + nt * 16 + l15;
                h2s[m * 136 + n] = (_Float16)fmaxf(acc2[mt][nt][r] + bias2[nt], 0.0f);
            }
    __syncthreads();

    // ---- layer 3 (MFMA): C[m=64][n=wv*16 .. +16]
    floatx4 acc3[4];
#pragma unroll
    for (int mt = 0; mt < 4; ++mt) acc3[mt] = (floatx4){0.f, 0.f, 0.f, 0.f};
#pragma unroll
    for (int ks = 0; ks < 4; ++ks)
#pragma unroll
        for (int mt = 0; mt < 4; ++mt) {
            const half8 a = *(const half8*)&h2s[(mt * 16 + l15) * 136 + ks * 32 + quad * 8];
            acc3[mt] = __builtin_amdgcn_mfma_f32_16x16x32_f16(a, b3f[ks], acc3[mt], 0, 0, 0);
        }

    // ---- layer 4: per-lane relu+dot, reduce over the 16 n's in each quad
    const float bias3 = b3[n3];
    const float w4v = W4[n3];
#pragma unroll
    for (int mt = 0; mt < 4; ++mt)
#pragma unroll
        for (int r = 0; r < 4; ++r) {
            float v = fmaxf(acc3[mt][r] + bias3, 0.0f) * w4v;
            v += __int_as_float(__builtin_amdgcn_ds_swizzle(__float_as_int(v), 0x041F));
            v += __int_as_float(__builtin_amdgcn_ds_swizzle(__float_as_int(v), 0x081F));
            v += __int_as_float(__builtin_amdgcn_ds_swizzle(__float_as_int(v), 0x101F));
            v += __int_as_float(__builtin_amdgcn_ds_swizzle(__float_as_int(v), 0x201F));
            if (l15 == 0) partial[wv * 64 + mt * 16 + quad * 4 + r] = v;
        }
    __syncthreads();

    if (t < 64) {  // wave 0: d_edge is dist_in[e0+t] already in register
        const float s = partial[t] + partial[64 + t] + partial[128 + t] + partial[192 + t] + b4[0];
        out[e0 + t] = (d_edge <= 1.0f) ? s : 0.0f;
    }
}

extern "C" void kernel_launch(void* const* d_in, const int* in_sizes, int n_in,
                              void* d_out, int out_size, void* d_ws, size_t ws_size,
                              hipStream_t stream) {
    const float* states = (const float*)d_in[0];
    const float* W1 = (const float*)d_in[1];
    const float* b1 = (const float*)d_in[2];
    const float* W2 = (const float*)d_in[3];
    const float* b2 = (const float*)d_in[4];
    const float* W3 = (const float*)d_in[5];
    const float* b3 = (const float*)d_in[6];
    const float* W4 = (const float*)d_in[7];
    const float* b4 = (const float*)d_in[8];

    char* ws = (char*)d_ws;
    int* idx = (int*)ws;                           // 192 KB
    float* dist = (float*)(ws + 192 * 1024);       // 192 KB
    _Float16* W2T = (_Float16*)(ws + 384 * 1024);  // 16 KB  [n=128][k=64]
    _Float16* W3T = (_Float16*)(ws + 400 * 1024);  // 16 KB  [n=64][k=128]

    topk_kernel<<<N_AGENTS / 2 + 2, 256, 0, stream>>>(states, W2, W3, W2T, W3T, idx, dist);
    mlp_kernel<<<(N_AGENTS * TOPK) / 64, 256, 0, stream>>>(
        states, idx, dist, W1, b1, W2T, b2, W3T, b3, W4, b4, (float*)d_out);
}